// Round 11
// baseline (954.466 us; speedup 1.0000x reference)
//
#include <hip/hip_runtime.h>

#define N_VOX 200000
#define K_OFF 27
#define P_PAIR 400000
#define C_IN 32
#define C_MID 64
#define C_OUT 32
#define PPB 320            // 4 waves x 5 tiles x 16 pairs; 400000 % 320 == 0
#define TILES_PER_WAVE 5
#define FEAT_BLKS (N_VOX * C_IN / 4 / 256)   // 6250

typedef __attribute__((ext_vector_type(8))) short short8;
typedef __attribute__((ext_vector_type(4))) float f32x4;
typedef __attribute__((ext_vector_type(4))) unsigned int u32x4;

__device__ inline unsigned short f2bf(float f) {
    union { float f; unsigned u; } v; v.f = f;
    unsigned r = v.u + 0x7FFF + ((v.u >> 16) & 1);   // RNE
    return (unsigned short)(r >> 16);
}

// packed bf16 atomic: mem[p] += lo, mem[p+1] += hi  (one TCC atomic op)
__device__ inline void pk_add_bf16(unsigned short* p, float lo, float hi) {
    const unsigned d = (unsigned)f2bf(lo) | ((unsigned)f2bf(hi) << 16);
    asm volatile("global_atomic_pk_add_bf16 %0, %1, off" :: "v"(p), "v"(d) : "memory");
}

// ReLU on 8 packed bf16 (R10 relu_h bit-trick, applied at gather time)
__device__ inline short8 relu_bf16x8(short8 x) {
    u32x4 v = *(u32x4*)&x;
#pragma unroll
    for (int c = 0; c < 4; ++c) {
        unsigned m = v[c] & 0x80008000u;             // sign bits per half
        m |= m >> 1; m |= m >> 2; m |= m >> 4; m |= m >> 8;  // spread to 0xFFFF
        v[c] &= ~m;                                  // negative halves -> +0
    }
    return *(short8*)&v;
}

// ---------- prep: feats f32->bf16  +  W -> fragment tables (fused) --------
// W permutation (PK-friendly, R10-proven):
// conv1 frag (k,nt), lane(g,r), j: col = 2r + (nt&1) + 32*(nt>>1), row = g*8+j
// conv2 frag (k,nt,ks):           col = 2r + nt,        row = ks*32 + g*8 + j
__global__ __launch_bounds__(256) void prep(
    const float* __restrict__ feats,
    const float* __restrict__ W_in, const float* __restrict__ W_out,
    unsigned short* __restrict__ featsb,
    short* __restrict__ Wb1, short* __restrict__ Wb2)
{
    if (blockIdx.x < FEAT_BLKS) {
        const int i = blockIdx.x * 256 + threadIdx.x;
        f32x4 v = ((const f32x4*)feats)[i];
        ((unsigned int*)featsb)[2*i]   = (unsigned)f2bf(v[0]) | ((unsigned)f2bf(v[1]) << 16);
        ((unsigned int*)featsb)[2*i+1] = (unsigned)f2bf(v[2]) | ((unsigned)f2bf(v[3]) << 16);
        return;
    }
    const int fb   = (blockIdx.x - FEAT_BLKS) * 4 + (threadIdx.x >> 6);
    const int lane = threadIdx.x & 63;
    if (fb >= 216) return;
    const int g = lane >> 4, r = lane & 15;
    short8 o;
    if (fb < 108) {                                  // conv1: k=fb>>2, nt=fb&3
        const int k = fb >> 2, nt = fb & 3;
        const int col = 2 * r + (nt & 1) + 32 * (nt >> 1);
        const float* Wk = W_in + (size_t)k * (C_IN * C_MID);
#pragma unroll
        for (int j = 0; j < 8; ++j) o[j] = (short)f2bf(Wk[(g*8+j)*C_MID + col]);
        *(short8*)(Wb1 + (size_t)(fb * 64 + lane) * 8) = o;
    } else {                                         // conv2: q=nt*2+ks
        const int b2 = fb - 108, k = b2 >> 2, q = b2 & 3;
        const int nt = q >> 1, ks = q & 1;
        const int col = 2 * r + nt;
        const float* Wk = W_out + (size_t)k * (C_MID * C_OUT);
#pragma unroll
        for (int j = 0; j < 8; ++j) o[j] = (short)f2bf(Wk[(ks*32 + g*8 + j)*C_OUT + col]);
        *(short8*)(Wb2 + (size_t)(b2 * 64 + lane) * 8) = o;
    }
}

// ---------- conv1: R3 streaming structure, pk-bf16 scatter ----------
// MFMA 16x16x32 bf16; A: lane(g,r) = pair pbase+r, ch g*8..+7 (one short8).
// C/D row m=4g+i (pair); "col" r -> channel pairs via the W permutation.
__global__ __launch_bounds__(256) void conv1_mfma(
    const unsigned short* __restrict__ featsb,
    const int*   __restrict__ in_idx,
    const int*   __restrict__ out_idx,
    const float* __restrict__ mask,
    const short* __restrict__ Wb1,
    unsigned short* __restrict__ h)
{
    const int k    = blockIdx.x;
    const int lane = threadIdx.x & 63;
    const int wave = threadIdx.x >> 6;
    const int g    = lane >> 4;
    const int r    = lane & 15;
    const size_t koff = (size_t)k * P_PAIR;

    const short8* wp = (const short8*)Wb1 + (size_t)(k * 4) * 64 + lane;
    const short8 f0 = wp[0], f1 = wp[64], f2 = wp[128], f3 = wp[192];

    const int wbase = blockIdx.y * PPB + wave * (PPB / 4);
#pragma unroll 1
    for (int t = 0; t < TILES_PER_WAVE; ++t) {
        const int pbase = wbase + t * 16;
        const int pr = pbase + r;
        const bool avalid = (mask[koff + pr] > 0.5f);

        short8 a = {};
        if (avalid)
            a = *(const short8*)(featsb + (size_t)in_idx[koff + pr] * C_IN + g * 8);

        f32x4 acc0 = {}, acc1 = {}, acc2 = {}, acc3 = {};
        acc0 = __builtin_amdgcn_mfma_f32_16x16x32_bf16(a, f0, acc0, 0, 0, 0);
        acc1 = __builtin_amdgcn_mfma_f32_16x16x32_bf16(a, f1, acc1, 0, 0, 0);
        acc2 = __builtin_amdgcn_mfma_f32_16x16x32_bf16(a, f2, acc2, 0, 0, 0);
        acc3 = __builtin_amdgcn_mfma_f32_16x16x32_bf16(a, f3, acc3, 0, 0, 0);

#pragma unroll
        for (int i = 0; i < 4; ++i) {
            const int m = g * 4 + i;                 // this lane's C/D rows
            const size_t e = koff + pbase + m;
            if (mask[e] > 0.5f) {                    // ground-truth re-read (L1-hot)
                unsigned short* hp = h + (size_t)out_idx[e] * C_MID + 2 * r;
                pk_add_bf16(hp,      acc0[i], acc1[i]);   // ch 2r, 2r+1
                pk_add_bf16(hp + 32, acc2[i], acc3[i]);   // ch 32+2r, 33+2r
            }
        }
    }
}

// ---------- conv2: K=64 (2 k-steps), ReLU fused at gather, pk scatter ------
__global__ __launch_bounds__(256) void conv2_mfma(
    const unsigned short* __restrict__ hb,
    const int*   __restrict__ in_idx,
    const int*   __restrict__ out_idx,
    const float* __restrict__ mask,
    const short* __restrict__ Wb2,
    unsigned short* __restrict__ outw)
{
    const int k    = blockIdx.x;
    const int lane = threadIdx.x & 63;
    const int wave = threadIdx.x >> 6;
    const int g    = lane >> 4;
    const int r    = lane & 15;
    const size_t koff = (size_t)k * P_PAIR;

    const short8* wp = (const short8*)Wb2 + (size_t)(k * 4) * 64 + lane;
    const short8 f00 = wp[0], f01 = wp[64], f10 = wp[128], f11 = wp[192];

    const int wbase = blockIdx.y * PPB + wave * (PPB / 4);
#pragma unroll 1
    for (int t = 0; t < TILES_PER_WAVE; ++t) {
        const int pbase = wbase + t * 16;
        const int pr = pbase + r;
        const bool avalid = (mask[koff + pr] > 0.5f);

        short8 a0 = {}, a1 = {};
        if (avalid) {
            const short8* row = (const short8*)(hb + (size_t)in_idx[koff + pr] * C_MID);
            a0 = relu_bf16x8(row[g]);                // ch g*8..+7   (k-step 0)
            a1 = relu_bf16x8(row[4 + g]);            // ch 32+g*8..  (k-step 1)
        }

        f32x4 acc0 = {}, acc1 = {};
        acc0 = __builtin_amdgcn_mfma_f32_16x16x32_bf16(a0, f00, acc0, 0, 0, 0);
        acc0 = __builtin_amdgcn_mfma_f32_16x16x32_bf16(a1, f01, acc0, 0, 0, 0);
        acc1 = __builtin_amdgcn_mfma_f32_16x16x32_bf16(a0, f10, acc1, 0, 0, 0);
        acc1 = __builtin_amdgcn_mfma_f32_16x16x32_bf16(a1, f11, acc1, 0, 0, 0);

#pragma unroll
        for (int i = 0; i < 4; ++i) {
            const int m = g * 4 + i;
            const size_t e = koff + pbase + m;
            if (mask[e] > 0.5f) {
                unsigned short* op = outw + (size_t)out_idx[e] * C_OUT + 2 * r;
                pk_add_bf16(op, acc0[i], acc1[i]);   // ch 2r, 2r+1
            }
        }
    }
}

// ---------- out_ws bf16 -> d_out f32 ----------
__global__ __launch_bounds__(256) void cvt_out(
    const unsigned int* __restrict__ outw, float* __restrict__ out)
{
    const int i = blockIdx.x * 256 + threadIdx.x;    // grid exact: 6250 blocks
    const unsigned v0 = outw[2 * i], v1 = outw[2 * i + 1];
    union { unsigned u; float f; } a, b, c, d;
    a.u = v0 << 16; b.u = v0 & 0xFFFF0000u;
    c.u = v1 << 16; d.u = v1 & 0xFFFF0000u;
    f32x4 o = { a.f, b.f, c.f, d.f };
    ((f32x4*)out)[i] = o;
}

// ---------------------------------------------------------------------------
extern "C" void kernel_launch(void* const* d_in, const int* in_sizes, int n_in,
                              void* d_out, int out_size, void* d_ws, size_t ws_size,
                              hipStream_t stream) {
    const float* feats   = (const float*)d_in[0];
    const int*   in_idx  = (const int*)  d_in[1];
    const int*   out_idx = (const int*)  d_in[2];
    const float* mask    = (const float*)d_in[3];
    const float* W_in    = (const float*)d_in[4];
    const float* W_out   = (const float*)d_in[5];
    float* out = (float*)d_out;

    // ws layout (bytes): h_bf16 | feats_bf16 | out_bf16 | Wb1 | Wb2
    char* ws = (char*)d_ws;
    unsigned short* h      = (unsigned short*)(ws);               // 25,600,000
    unsigned short* featsb = (unsigned short*)(ws + 25600000);    // 12,800,000
    unsigned short* outw   = (unsigned short*)(ws + 38400000);    // 12,800,000
    short* Wb1 = (short*)(ws + 51200000);                         //    110,592
    short* Wb2 = (short*)(ws + 51310592);                         //    110,592

    hipMemsetAsync(h,    0, (size_t)N_VOX * C_MID * 2, stream);
    hipMemsetAsync(outw, 0, (size_t)N_VOX * C_OUT * 2, stream);

    prep<<<FEAT_BLKS + 54, 256, 0, stream>>>(feats, W_in, W_out, featsb, Wb1, Wb2);

    dim3 grid(K_OFF, P_PAIR / PPB);                               // (27, 1250)
    conv1_mfma<<<grid, 256, 0, stream>>>(featsb, in_idx, out_idx, mask, Wb1, h);
    conv2_mfma<<<grid, 256, 0, stream>>>(h, in_idx, out_idx, mask, Wb2, outw);
    cvt_out<<<N_VOX * C_OUT / 4 / 256, 256, 0, stream>>>((const unsigned int*)outw, out);
}